// Round 11
// baseline (277.620 us; speedup 1.0000x reference)
//
#include <hip/hip_runtime.h>

#define N_NODES 50000
#define IN_DIM 512
#define HIDDEN 64
#define OUT_DIM 47
#define HSTRIDE 448  // hcat row stride (bf16): [h0(64) | hA(128) | hB(256)]

#define NBINS 782    // ceil(50000/64); bin = dst >> 6 (64 nodes/bin)
#define CAP1 1536    // staging cap/bin list1 (mean 1023, +16 sigma)
#define CAP2 2048    // staging cap/bin list2 (mean 1534, +13 sigma)
#define CHUNK 4096

typedef unsigned short u16;
typedef short v8s __attribute__((ext_vector_type(8)));
typedef float v4f __attribute__((ext_vector_type(4)));

union F4 { float4 v; float f[4]; };
union U4 { uint4 v; unsigned u[4]; };

static __device__ __forceinline__ u16 f2bf(float f) {
  unsigned u = __float_as_uint(f);
  u += 0x7fffu + ((u >> 16) & 1u);
  return (u16)(u >> 16);
}
static __device__ __forceinline__ float bf2f(u16 h) {
  return __uint_as_float(((unsigned)h) << 16);
}

// ---------------------------------------------------------------------------
// prep_scatter (fused): [0,16) conv embed_w hi/lo; [16,27) conv cls_w;
// rest: binned edge scatter into staging (one global atomic per block,bin).
// staging payload 8B: x = src | (dstLocal<<16), y = w bits.
// ---------------------------------------------------------------------------
__global__ __launch_bounds__(256) void prep_scatter(
    const float* __restrict__ embed_w, u16* __restrict__ weTh,
    u16* __restrict__ weTl, const float* __restrict__ cls_w,
    u16* __restrict__ wcTh, u16* __restrict__ wcTl,
    const int* __restrict__ src1, const int* __restrict__ dst1,
    const float* __restrict__ w1, int E1, int c1,
    const int* __restrict__ src2, const int* __restrict__ dst2,
    const float* __restrict__ w2, int E2,
    int* __restrict__ binCursor, int2* __restrict__ stg1,
    int2* __restrict__ stg2) {
  int b = blockIdx.x;
  if (b < 16) {
    int tid = b * 256 + threadIdx.x;  // 64 cols * 64 kgroups
    int col = tid >> 6;
    int k8 = (tid & 63) * 8;
#pragma unroll
    for (int j = 0; j < 8; j++) {
      float v = embed_w[(size_t)(k8 + j) * HIDDEN + col];
      u16 h = f2bf(v);
      weTh[(size_t)col * IN_DIM + k8 + j] = h;
      weTl[(size_t)col * IN_DIM + k8 + j] = f2bf(v - bf2f(h));
    }
    return;
  }
  if (b < 27) {
    int tid = (b - 16) * 256 + threadIdx.x;  // 48 cols * 56 kgroups
    if (tid < 48 * 56) {
      int col = tid / 56;
      int k8 = (tid % 56) * 8;
#pragma unroll
      for (int j = 0; j < 8; j++) {
        float v = (col < OUT_DIM) ? cls_w[(size_t)(k8 + j) * OUT_DIM + col] : 0.f;
        u16 h = f2bf(v);
        wcTh[(size_t)col * HSTRIDE + k8 + j] = h;
        wcTl[(size_t)col * HSTRIDE + k8 + j] = f2bf(v - bf2f(h));
      }
    }
    return;
  }

  int q = b - 27;
  const int *src, *dst;
  const float* w;
  int E, cap;
  int2* stg;
  int* bc;
  if (q < c1) {
    src = src1; dst = dst1; w = w1; E = E1; stg = stg1; bc = binCursor; cap = CAP1;
  } else {
    q -= c1;
    src = src2; dst = dst2; w = w2; E = E2; stg = stg2; bc = binCursor + NBINS; cap = CAP2;
  }
  int e0 = q * CHUNK;
  int n = E - e0;
  if (n > CHUNK) n = CHUNK;

  __shared__ int hist[NBINS], segrel[NBINS], cur[NBINS];
  for (int i = threadIdx.x; i < NBINS; i += 256) { hist[i] = 0; cur[i] = 0; }
  __syncthreads();
  for (int t = threadIdx.x; t < n; t += 256)
    atomicAdd(&hist[dst[e0 + t] >> 6], 1);
  __syncthreads();
  for (int i = threadIdx.x; i < NBINS; i += 256) {
    int h = hist[i];
    segrel[i] = h ? atomicAdd(&bc[i], h) : 0;
  }
  __syncthreads();
  for (int t = threadIdx.x; t < n; t += 256) {
    int d = dst[e0 + t];
    int bin = d >> 6;
    int rel = segrel[bin] + atomicAdd(&cur[bin], 1);
    if (rel < cap)
      stg[(size_t)bin * cap + rel] =
          make_int2(src[e0 + t] | ((d & 63) << 16), __float_as_int(w[e0 + t]));
  }
}

// ---------------------------------------------------------------------------
// binscan: exclusive scan of the NBINS (782) bin counts per list (grid=2).
// ---------------------------------------------------------------------------
__global__ __launch_bounds__(1024) void binscan(const int* __restrict__ cnt,
                                                int* __restrict__ scanout) {
  const int* in = cnt + blockIdx.x * NBINS;
  int* out = scanout + blockIdx.x * NBINS;
  int tid = threadIdx.x, lane = tid & 63, wid = tid >> 6;
  __shared__ int wsum[16];
  int v0 = (tid < NBINS) ? in[tid] : 0;
  int v = v0;
#pragma unroll
  for (int off = 1; off < 64; off <<= 1) {
    int t = __shfl_up(v, off, 64);
    if (lane >= off) v += t;
  }
  if (lane == 63) wsum[wid] = v;
  __syncthreads();
  if (tid < 16) {
    int s = wsum[tid], sc = s;
#pragma unroll
    for (int off = 1; off < 16; off <<= 1) {
      int t = __shfl_up(sc, off, 16);
      if (tid >= off) sc += t;
    }
    wsum[tid] = sc - s;
  }
  __syncthreads();
  if (tid < NBINS) out[tid] = v - v0 + wsum[wid];
}

// ---------------------------------------------------------------------------
// embed_place (fused, 512 threads): blocks [0,782) = embed MFMA (64 rows x
// 64 cols per block; 8 waves of 16 rows x 32 cols) -> hcat[:,0:64] bf16;
// blocks [782, 782+2*NBINS) = per-bin CSR placement (64-node bins).
// embed A: fp32 x -> single bf16 convert; B hi/lo split (2 MFMA/nf).
// C/D: col=lane&15, row=(lane>>4)*4+reg  [m89-verified]
// ---------------------------------------------------------------------------
__global__ __launch_bounds__(512) void embed_place(
    const float* __restrict__ x, const u16* __restrict__ wTh,
    const u16* __restrict__ wTl, const float* __restrict__ bias,
    u16* __restrict__ hcat, const int* __restrict__ binCursor,
    const int* __restrict__ binScan, const int2* __restrict__ stg1,
    int2* __restrict__ ew1, int* __restrict__ ep1,
    const int2* __restrict__ stg2, int2* __restrict__ ew2,
    int* __restrict__ ep2) {
  int b = blockIdx.x;
  if (b < 782) {
    int wave = threadIdx.x >> 6, lane = threadIdx.x & 63;
    int rowgrp = wave >> 1, colgrp = wave & 1;  // 4 row-grps x 2 col-grps
    int row0 = b * 64 + rowgrp * 16;
    int m = lane & 15, kq = lane >> 4;
    int rowA = row0 + m;
    if (rowA >= N_NODES) rowA = N_NODES - 1;
    const float* xr = x + (size_t)rowA * IN_DIM;

    v4f acc[2];
    acc[0] = (v4f){0.f, 0.f, 0.f, 0.f};
    acc[1] = (v4f){0.f, 0.f, 0.f, 0.f};

#pragma unroll 4
    for (int k0 = 0; k0 < IN_DIM; k0 += 32) {
      int kk = k0 + kq * 8;
      F4 p, qv;
      p.v = *(const float4*)(xr + kk);
      qv.v = *(const float4*)(xr + kk + 4);
      v8s a;
#pragma unroll
      for (int j = 0; j < 4; j++) {
        a[j] = (short)f2bf(p.f[j]);
        a[4 + j] = (short)f2bf(qv.f[j]);
      }
#pragma unroll
      for (int nf = 0; nf < 2; nf++) {
        int col = colgrp * 32 + nf * 16 + m;
        v8s bh = *(const v8s*)(wTh + (size_t)col * IN_DIM + kk);
        v8s bl = *(const v8s*)(wTl + (size_t)col * IN_DIM + kk);
        acc[nf] = __builtin_amdgcn_mfma_f32_16x16x32_bf16(a, bh, acc[nf], 0, 0, 0);
        acc[nf] = __builtin_amdgcn_mfma_f32_16x16x32_bf16(a, bl, acc[nf], 0, 0, 0);
      }
    }

#pragma unroll
    for (int nf = 0; nf < 2; nf++) {
      int col = colgrp * 32 + nf * 16 + m;
      float bv = bias[col];
#pragma unroll
      for (int reg = 0; reg < 4; reg++) {
        int rowC = row0 + kq * 4 + reg;
        if (rowC < N_NODES) {
          float v = acc[nf][reg] + bv;
          hcat[(size_t)rowC * HSTRIDE + col] = f2bf(v > 0.f ? v : 0.f);
        }
      }
    }
    return;
  }

  int pb = b - 782;
  int lb = pb < NBINS ? pb : pb - NBINS;
  const int2* stg;
  int2* ew;
  int* ep;
  int cap;
  if (pb < NBINS) { stg = stg1; ew = ew1; ep = ep1; cap = CAP1; }
  else            { stg = stg2; ew = ew2; ep = ep2; cap = CAP2; }
  int cnt = binCursor[pb];
  if (cnt > cap) cnt = cap;
  int base = binScan[pb];
  const int2* seg = stg + (size_t)lb * cap;
  int node0 = lb << 6;
  int nnodes = N_NODES - node0;
  if (nnodes > 64) nnodes = 64;

  __shared__ int ncnt[64], noff[64], ncur[64];
  if (threadIdx.x < 64) { ncnt[threadIdx.x] = 0; ncur[threadIdx.x] = 0; }
  __syncthreads();
  for (int t = threadIdx.x; t < cnt; t += 512)
    atomicAdd(&ncnt[(seg[t].x >> 16) & 63], 1);
  __syncthreads();
  if (threadIdx.x < 64) {
    int v0 = ncnt[threadIdx.x];
    int v = v0;
#pragma unroll
    for (int off = 1; off < 64; off <<= 1) {
      int t = __shfl_up(v, off, 64);
      if (threadIdx.x >= (unsigned)off) v += t;
    }
    noff[threadIdx.x] = v - v0;  // exclusive
    if (threadIdx.x < nnodes) ep[node0 + threadIdx.x] = base + v;  // inclusive
  }
  __syncthreads();
  for (int t = threadIdx.x; t < cnt; t += 512) {
    int2 pk = seg[t];
    int nl = (pk.x >> 16) & 63;
    int pos = base + noff[nl] + atomicAdd(&ncur[nl], 1);
    ew[pos] = make_int2(pk.x & 0xFFFF, pk.y);
  }
}

// ---------------------------------------------------------------------------
// gather2 (fused pair): blocks [0,half) = list1 -> out1, rest = list2 -> out2.
// NT threads/node, each 8 bf16 cols (16B load/edge). fp32 acc, ReLU, bf16 out.
// ---------------------------------------------------------------------------
__device__ __forceinline__ void bf8_fma(const U4& r, float wt, float* a) {
#pragma unroll
  for (int i = 0; i < 4; i++) {
    a[2 * i]     += wt * __uint_as_float(r.u[i] << 16);
    a[2 * i + 1] += wt * __uint_as_float(r.u[i] & 0xffff0000u);
  }
}

template <int NT>
__global__ __launch_bounds__(256) void gather2(
    const int* __restrict__ ep1, const int2* __restrict__ ew1,
    const int* __restrict__ ep2, const int2* __restrict__ ew2,
    const u16* __restrict__ hin, u16* __restrict__ out1,
    u16* __restrict__ out2, int half_blocks) {
  int b = blockIdx.x;
  const int* ep;
  const int2* ew;
  u16* out;
  if (b < half_blocks) { ep = ep1; ew = ew1; out = out1; }
  else { b -= half_blocks; ep = ep2; ew = ew2; out = out2; }

  int tid = b * 256 + threadIdx.x;
  int node = tid / NT;
  if (node >= N_NODES) return;
  int col0 = (tid % NT) * 8;
  int s = node ? ep[node - 1] : 0;
  int e = ep[node];

  float a0[8], a1[8];
#pragma unroll
  for (int i = 0; i < 8; i++) { a0[i] = 0.f; a1[i] = 0.f; }

  int j = s;
  for (; j + 4 <= e; j += 4) {
    int2 p0 = ew[j], p1 = ew[j + 1], p2 = ew[j + 2], p3 = ew[j + 3];
    U4 r0, r1, r2, r3;
    r0.v = *(const uint4*)(hin + (size_t)p0.x * HSTRIDE + col0);
    r1.v = *(const uint4*)(hin + (size_t)p1.x * HSTRIDE + col0);
    r2.v = *(const uint4*)(hin + (size_t)p2.x * HSTRIDE + col0);
    r3.v = *(const uint4*)(hin + (size_t)p3.x * HSTRIDE + col0);
    bf8_fma(r0, __int_as_float(p0.y), a0);
    bf8_fma(r1, __int_as_float(p1.y), a1);
    bf8_fma(r2, __int_as_float(p2.y), a0);
    bf8_fma(r3, __int_as_float(p3.y), a1);
  }
  for (; j < e; j++) {
    int2 p = ew[j];
    U4 r;
    r.v = *(const uint4*)(hin + (size_t)p.x * HSTRIDE + col0);
    bf8_fma(r, __int_as_float(p.y), a0);
  }

  U4 o;
#pragma unroll
  for (int i = 0; i < 4; i++) {
    float lo = a0[2 * i] + a1[2 * i];
    float hi = a0[2 * i + 1] + a1[2 * i + 1];
    lo = lo > 0.f ? lo : 0.f;
    hi = hi > 0.f ? hi : 0.f;
    o.u[i] = ((unsigned)f2bf(hi) << 16) | (unsigned)f2bf(lo);
  }
  *(uint4*)(out + (size_t)node * HSTRIDE + col0) = o.v;
}

// ---------------------------------------------------------------------------
// final: out = hcat(bf16) @ cls_w + b. A direct bf16, B split hi/lo (2 MFMA).
// ---------------------------------------------------------------------------
__global__ __launch_bounds__(256) void final_mfma(
    const u16* __restrict__ hcat, const u16* __restrict__ wTh,
    const u16* __restrict__ wTl, const float* __restrict__ bias,
    float* __restrict__ out) {
  int wave = threadIdx.x >> 6, lane = threadIdx.x & 63;
  int row0 = blockIdx.x * 64 + wave * 16;
  int m = lane & 15, kq = lane >> 4;
  int rowA = row0 + m;
  if (rowA >= N_NODES) rowA = N_NODES - 1;
  const u16* hr = hcat + (size_t)rowA * HSTRIDE;

  v4f acc[3];
#pragma unroll
  for (int nf = 0; nf < 3; nf++) acc[nf] = (v4f){0.f, 0.f, 0.f, 0.f};

#pragma unroll 2
  for (int k0 = 0; k0 < HSTRIDE; k0 += 32) {
    int kk = k0 + kq * 8;
    v8s a = *(const v8s*)(hr + kk);
#pragma unroll
    for (int nf = 0; nf < 3; nf++) {
      int col = nf * 16 + m;
      v8s bh = *(const v8s*)(wTh + (size_t)col * HSTRIDE + kk);
      v8s bl = *(const v8s*)(wTl + (size_t)col * HSTRIDE + kk);
      acc[nf] = __builtin_amdgcn_mfma_f32_16x16x32_bf16(a, bh, acc[nf], 0, 0, 0);
      acc[nf] = __builtin_amdgcn_mfma_f32_16x16x32_bf16(a, bl, acc[nf], 0, 0, 0);
    }
  }

#pragma unroll
  for (int nf = 0; nf < 3; nf++) {
    int col = nf * 16 + m;
    if (col < OUT_DIM) {
      float bv = bias[col];
#pragma unroll
      for (int reg = 0; reg < 4; reg++) {
        int rowC = row0 + kq * 4 + reg;
        if (rowC < N_NODES)
          out[(size_t)rowC * OUT_DIM + col] = acc[nf][reg] + bv;
      }
    }
  }
}

// ---------------------------------------------------------------------------
extern "C" void kernel_launch(void* const* d_in, const int* in_sizes, int n_in,
                              void* d_out, int out_size, void* d_ws,
                              size_t ws_size, hipStream_t stream) {
  const float* x       = (const float*)d_in[0];
  const int*   src1    = (const int*)d_in[1];
  const int*   dst1    = (const int*)d_in[2];
  const float* w1      = (const float*)d_in[3];
  const int*   src2    = (const int*)d_in[4];
  const int*   dst2    = (const int*)d_in[5];
  const float* w2      = (const float*)d_in[6];
  const float* embed_w = (const float*)d_in[7];
  const float* embed_b = (const float*)d_in[8];
  const float* cls_w   = (const float*)d_in[9];
  const float* cls_b   = (const float*)d_in[10];
  int E1 = in_sizes[1];
  int E2 = in_sizes[4];

  float* ws = (float*)d_ws;
  size_t off = 0;
  u16* hcat = (u16*)(ws + off); off += (size_t)N_NODES * HSTRIDE / 2;
  int2* ew1 = (int2*)(ws + off); off += (size_t)2 * E1;
  int2* ew2 = (int2*)(ws + off); off += (size_t)2 * E2;
  int* ep1 = (int*)(ws + off); off += N_NODES;
  int* ep2 = (int*)(ws + off); off += N_NODES;
  int2* stg1 = (int2*)(ws + off); off += (size_t)2 * NBINS * CAP1;
  int2* stg2 = (int2*)(ws + off); off += (size_t)2 * NBINS * CAP2;
  int* binCursor = (int*)(ws + off); off += 2 * NBINS;
  int* binScan = (int*)(ws + off); off += 2 * NBINS;
  u16* weTh = (u16*)(ws + off); off += 16384;
  u16* weTl = (u16*)(ws + off); off += 16384;
  u16* wcTh = (u16*)(ws + off); off += 10752;
  u16* wcTl = (u16*)(ws + off); off += 10752;

  int c1 = (E1 + CHUNK - 1) / CHUNK;
  int c2 = (E2 + CHUNK - 1) / CHUNK;

  hipMemsetAsync(binCursor, 0, 2 * NBINS * sizeof(int), stream);
  prep_scatter<<<27 + c1 + c2, 256, 0, stream>>>(
      embed_w, weTh, weTl, cls_w, wcTh, wcTl,
      src1, dst1, w1, E1, c1, src2, dst2, w2, E2,
      binCursor, stg1, stg2);
  binscan<<<2, 1024, 0, stream>>>(binCursor, binScan);
  embed_place<<<782 + 2 * NBINS, 512, 0, stream>>>(
      x, weTh, weTl, embed_b, hcat, binCursor, binScan,
      stg1, ew1, ep1, stg2, ew2, ep2);
  // k=1: cols 64:128 <- A1 @ hcat[:,0:64]; cols 128:192 <- A2 @ same
  gather2<8><<<3126, 256, 0, stream>>>(ep1, ew1, ep2, ew2, hcat,
                                       hcat + 64, hcat + 128, 1563);
  // k=2: cols 192:320 <- A1 @ hcat[:,64:192]; cols 320:448 <- A2 @ same
  gather2<16><<<6250, 256, 0, stream>>>(ep1, ew1, ep2, ew2, hcat + 64,
                                        hcat + 192, hcat + 320, 3125);
  final_mfma<<<782, 256, 0, stream>>>(hcat, wcTh, wcTl, cls_b, (float*)d_out);
}

// Round 12
// 263.368 us; speedup vs baseline: 1.0541x; 1.0541x over previous
//
#include <hip/hip_runtime.h>

#define N_NODES 50000
#define IN_DIM 512
#define HIDDEN 64
#define OUT_DIM 47
#define HSTRIDE 448  // hcat row stride (bf16): [h0(64) | hA(128) | hB(256)]

#define NBINS 391    // ceil(50000/128); bin = dst >> 7
#define CAP1 3072
#define CAP2 4096
#define CHUNK 4096

typedef unsigned short u16;
typedef short v8s __attribute__((ext_vector_type(8)));
typedef float v4f __attribute__((ext_vector_type(4)));

union F4 { float4 v; float f[4]; };
union U4 { uint4 v; unsigned u[4]; };

static __device__ __forceinline__ u16 f2bf(float f) {
  unsigned u = __float_as_uint(f);
  u += 0x7fffu + ((u >> 16) & 1u);
  return (u16)(u >> 16);
}
static __device__ __forceinline__ float bf2f(u16 h) {
  return __uint_as_float(((unsigned)h) << 16);
}

// ---------------------------------------------------------------------------
// prep_scatter (fused): [0,16) conv embed_w hi/lo; [16,27) conv cls_w;
// rest: binned edge scatter into staging (one global atomic per block,bin).
// staging payload 8B: x = src | (dstLocal<<16), y = w bits.
// ---------------------------------------------------------------------------
__global__ __launch_bounds__(256) void prep_scatter(
    const float* __restrict__ embed_w, u16* __restrict__ weTh,
    u16* __restrict__ weTl, const float* __restrict__ cls_w,
    u16* __restrict__ wcTh, u16* __restrict__ wcTl,
    const int* __restrict__ src1, const int* __restrict__ dst1,
    const float* __restrict__ w1, int E1, int c1,
    const int* __restrict__ src2, const int* __restrict__ dst2,
    const float* __restrict__ w2, int E2,
    int* __restrict__ binCursor, int2* __restrict__ stg1,
    int2* __restrict__ stg2) {
  int b = blockIdx.x;
  if (b < 16) {
    int tid = b * 256 + threadIdx.x;  // 64 cols * 64 kgroups
    int col = tid >> 6;
    int k8 = (tid & 63) * 8;
#pragma unroll
    for (int j = 0; j < 8; j++) {
      float v = embed_w[(size_t)(k8 + j) * HIDDEN + col];
      u16 h = f2bf(v);
      weTh[(size_t)col * IN_DIM + k8 + j] = h;
      weTl[(size_t)col * IN_DIM + k8 + j] = f2bf(v - bf2f(h));
    }
    return;
  }
  if (b < 27) {
    int tid = (b - 16) * 256 + threadIdx.x;  // 48 cols * 56 kgroups
    if (tid < 48 * 56) {
      int col = tid / 56;
      int k8 = (tid % 56) * 8;
#pragma unroll
      for (int j = 0; j < 8; j++) {
        float v = (col < OUT_DIM) ? cls_w[(size_t)(k8 + j) * OUT_DIM + col] : 0.f;
        u16 h = f2bf(v);
        wcTh[(size_t)col * HSTRIDE + k8 + j] = h;
        wcTl[(size_t)col * HSTRIDE + k8 + j] = f2bf(v - bf2f(h));
      }
    }
    return;
  }

  int q = b - 27;
  const int *src, *dst;
  const float* w;
  int E, cap;
  int2* stg;
  int* bc;
  if (q < c1) {
    src = src1; dst = dst1; w = w1; E = E1; stg = stg1; bc = binCursor; cap = CAP1;
  } else {
    q -= c1;
    src = src2; dst = dst2; w = w2; E = E2; stg = stg2; bc = binCursor + NBINS; cap = CAP2;
  }
  int e0 = q * CHUNK;
  int n = E - e0;
  if (n > CHUNK) n = CHUNK;

  __shared__ int hist[NBINS], segrel[NBINS], cur[NBINS];
  for (int i = threadIdx.x; i < NBINS; i += 256) { hist[i] = 0; cur[i] = 0; }
  __syncthreads();
  for (int t = threadIdx.x; t < n; t += 256)
    atomicAdd(&hist[dst[e0 + t] >> 7], 1);
  __syncthreads();
  for (int i = threadIdx.x; i < NBINS; i += 256) {
    int h = hist[i];
    segrel[i] = h ? atomicAdd(&bc[i], h) : 0;
  }
  __syncthreads();
  for (int t = threadIdx.x; t < n; t += 256) {
    int d = dst[e0 + t];
    int bin = d >> 7;
    int rel = segrel[bin] + atomicAdd(&cur[bin], 1);
    if (rel < cap)
      stg[(size_t)bin * cap + rel] =
          make_int2(src[e0 + t] | ((d & 127) << 16), __float_as_int(w[e0 + t]));
  }
}

// ---------------------------------------------------------------------------
// binscan: exclusive scan of the NBINS bin counts per list (grid=2).
// ---------------------------------------------------------------------------
__global__ __launch_bounds__(512) void binscan(const int* __restrict__ cnt,
                                               int* __restrict__ scanout) {
  const int* in = cnt + blockIdx.x * NBINS;
  int* out = scanout + blockIdx.x * NBINS;
  int tid = threadIdx.x, lane = tid & 63, wid = tid >> 6;
  __shared__ int wsum[8];
  int v0 = (tid < NBINS) ? in[tid] : 0;
  int v = v0;
#pragma unroll
  for (int off = 1; off < 64; off <<= 1) {
    int t = __shfl_up(v, off, 64);
    if (lane >= off) v += t;
  }
  if (lane == 63) wsum[wid] = v;
  __syncthreads();
  if (tid < 8) {
    int s = wsum[tid], sc = s;
#pragma unroll
    for (int off = 1; off < 8; off <<= 1) {
      int t = __shfl_up(sc, off, 8);
      if (tid >= off) sc += t;
    }
    wsum[tid] = sc - s;
  }
  __syncthreads();
  if (tid < NBINS) out[tid] = v - v0 + wsum[wid];
}

// ---------------------------------------------------------------------------
// embed_place (fused): blocks [0,782) = embed MFMA -> hcat[:,0:64] bf16;
// blocks [782, 782+2*NBINS) = per-bin CSR placement.
// embed: 128-k outer step, 8 batched x float4 loads in flight before
// convert+MFMA (latency fix, r12). A single bf16 convert; B hi/lo (2 MFMA/nf).
// C/D: col=lane&15, row=(lane>>4)*4+reg  [m89-verified]
// ---------------------------------------------------------------------------
__global__ __launch_bounds__(256) void embed_place(
    const float* __restrict__ x, const u16* __restrict__ wTh,
    const u16* __restrict__ wTl, const float* __restrict__ bias,
    u16* __restrict__ hcat, const int* __restrict__ binCursor,
    const int* __restrict__ binScan, const int2* __restrict__ stg1,
    int2* __restrict__ ew1, int* __restrict__ ep1,
    const int2* __restrict__ stg2, int2* __restrict__ ew2,
    int* __restrict__ ep2) {
  int b = blockIdx.x;
  if (b < 782) {
    int wave = threadIdx.x >> 6, lane = threadIdx.x & 63;
    int row0 = b * 64 + wave * 16;
    int m = lane & 15, kq = lane >> 4;
    int rowA = row0 + m;
    if (rowA >= N_NODES) rowA = N_NODES - 1;
    const float* xr = x + (size_t)rowA * IN_DIM;

    v4f acc[4];
#pragma unroll
    for (int nf = 0; nf < 4; nf++) acc[nf] = (v4f){0.f, 0.f, 0.f, 0.f};

#pragma unroll
    for (int k0 = 0; k0 < IN_DIM; k0 += 128) {
      // batch-issue 8 independent 16B x loads (4 chunks x 2)
      F4 xv[8];
#pragma unroll
      for (int c = 0; c < 4; c++) {
        int kk = k0 + c * 32 + kq * 8;
        xv[2 * c].v = *(const float4*)(xr + kk);
        xv[2 * c + 1].v = *(const float4*)(xr + kk + 4);
      }
#pragma unroll
      for (int c = 0; c < 4; c++) {
        int kk = k0 + c * 32 + kq * 8;
        v8s a;
#pragma unroll
        for (int j = 0; j < 4; j++) {
          a[j] = (short)f2bf(xv[2 * c].f[j]);
          a[4 + j] = (short)f2bf(xv[2 * c + 1].f[j]);
        }
#pragma unroll
        for (int nf = 0; nf < 4; nf++) {
          int col = nf * 16 + m;
          v8s bh = *(const v8s*)(wTh + (size_t)col * IN_DIM + kk);
          v8s bl = *(const v8s*)(wTl + (size_t)col * IN_DIM + kk);
          acc[nf] = __builtin_amdgcn_mfma_f32_16x16x32_bf16(a, bh, acc[nf], 0, 0, 0);
          acc[nf] = __builtin_amdgcn_mfma_f32_16x16x32_bf16(a, bl, acc[nf], 0, 0, 0);
        }
      }
    }

#pragma unroll
    for (int nf = 0; nf < 4; nf++) {
      int col = nf * 16 + m;
      float bv = bias[col];
#pragma unroll
      for (int reg = 0; reg < 4; reg++) {
        int rowC = row0 + kq * 4 + reg;
        if (rowC < N_NODES) {
          float v = acc[nf][reg] + bv;
          hcat[(size_t)rowC * HSTRIDE + col] = f2bf(v > 0.f ? v : 0.f);
        }
      }
    }
    return;
  }

  int bin = b - 782;
  int lb = bin < NBINS ? bin : bin - NBINS;
  const int2* stg;
  int2* ew;
  int* ep;
  int cap;
  if (bin < NBINS) { stg = stg1; ew = ew1; ep = ep1; cap = CAP1; }
  else             { stg = stg2; ew = ew2; ep = ep2; cap = CAP2; }
  int cnt = binCursor[bin];
  if (cnt > cap) cnt = cap;
  int base = binScan[bin];
  const int2* seg = stg + (size_t)lb * cap;
  int node0 = lb << 7;
  int nnodes = N_NODES - node0;
  if (nnodes > 128) nnodes = 128;

  __shared__ int ncnt[128], noff[128], ncur[128];
  __shared__ int t0;
  if (threadIdx.x < 128) { ncnt[threadIdx.x] = 0; ncur[threadIdx.x] = 0; }
  __syncthreads();
  for (int t = threadIdx.x; t < cnt; t += 256)
    atomicAdd(&ncnt[(seg[t].x >> 16) & 127], 1);
  __syncthreads();
  int v0 = 0, v = 0;
  if (threadIdx.x < 128) {
    v0 = ncnt[threadIdx.x];
    v = v0;
    int lane = threadIdx.x & 63;
#pragma unroll
    for (int off = 1; off < 64; off <<= 1) {
      int t = __shfl_up(v, off, 64);
      if (lane >= off) v += t;
    }
    if (threadIdx.x == 63) t0 = v;
  }
  __syncthreads();
  if (threadIdx.x < 128) {
    int excl = v - v0 + (threadIdx.x >= 64 ? t0 : 0);
    noff[threadIdx.x] = excl;
    if (threadIdx.x < nnodes) ep[node0 + threadIdx.x] = base + excl + v0;
  }
  __syncthreads();
  for (int t = threadIdx.x; t < cnt; t += 256) {
    int2 pk = seg[t];
    int nl = (pk.x >> 16) & 127;
    int pos = base + noff[nl] + atomicAdd(&ncur[nl], 1);
    ew[pos] = make_int2(pk.x & 0xFFFF, pk.y);
  }
}

// ---------------------------------------------------------------------------
// gather2 (fused pair): blocks [0,half) = list1 -> out1, rest = list2 -> out2.
// NT threads/node, each 8 bf16 cols (16B load/edge). fp32 acc, ReLU, bf16 out.
// ---------------------------------------------------------------------------
__device__ __forceinline__ void bf8_fma(const U4& r, float wt, float* a) {
#pragma unroll
  for (int i = 0; i < 4; i++) {
    a[2 * i]     += wt * __uint_as_float(r.u[i] << 16);
    a[2 * i + 1] += wt * __uint_as_float(r.u[i] & 0xffff0000u);
  }
}

template <int NT>
__global__ __launch_bounds__(256) void gather2(
    const int* __restrict__ ep1, const int2* __restrict__ ew1,
    const int* __restrict__ ep2, const int2* __restrict__ ew2,
    const u16* __restrict__ hin, u16* __restrict__ out1,
    u16* __restrict__ out2, int half_blocks) {
  int b = blockIdx.x;
  const int* ep;
  const int2* ew;
  u16* out;
  if (b < half_blocks) { ep = ep1; ew = ew1; out = out1; }
  else { b -= half_blocks; ep = ep2; ew = ew2; out = out2; }

  int tid = b * 256 + threadIdx.x;
  int node = tid / NT;
  if (node >= N_NODES) return;
  int col0 = (tid % NT) * 8;
  int s = node ? ep[node - 1] : 0;
  int e = ep[node];

  float a0[8], a1[8];
#pragma unroll
  for (int i = 0; i < 8; i++) { a0[i] = 0.f; a1[i] = 0.f; }

  int j = s;
  for (; j + 4 <= e; j += 4) {
    int2 p0 = ew[j], p1 = ew[j + 1], p2 = ew[j + 2], p3 = ew[j + 3];
    U4 r0, r1, r2, r3;
    r0.v = *(const uint4*)(hin + (size_t)p0.x * HSTRIDE + col0);
    r1.v = *(const uint4*)(hin + (size_t)p1.x * HSTRIDE + col0);
    r2.v = *(const uint4*)(hin + (size_t)p2.x * HSTRIDE + col0);
    r3.v = *(const uint4*)(hin + (size_t)p3.x * HSTRIDE + col0);
    bf8_fma(r0, __int_as_float(p0.y), a0);
    bf8_fma(r1, __int_as_float(p1.y), a1);
    bf8_fma(r2, __int_as_float(p2.y), a0);
    bf8_fma(r3, __int_as_float(p3.y), a1);
  }
  for (; j < e; j++) {
    int2 p = ew[j];
    U4 r;
    r.v = *(const uint4*)(hin + (size_t)p.x * HSTRIDE + col0);
    bf8_fma(r, __int_as_float(p.y), a0);
  }

  U4 o;
#pragma unroll
  for (int i = 0; i < 4; i++) {
    float lo = a0[2 * i] + a1[2 * i];
    float hi = a0[2 * i + 1] + a1[2 * i + 1];
    lo = lo > 0.f ? lo : 0.f;
    hi = hi > 0.f ? hi : 0.f;
    o.u[i] = ((unsigned)f2bf(hi) << 16) | (unsigned)f2bf(lo);
  }
  *(uint4*)(out + (size_t)node * HSTRIDE + col0) = o.v;
}

// ---------------------------------------------------------------------------
// final: out = hcat(bf16) @ cls_w + b. A direct bf16, B split hi/lo (2 MFMA).
// ---------------------------------------------------------------------------
__global__ __launch_bounds__(256) void final_mfma(
    const u16* __restrict__ hcat, const u16* __restrict__ wTh,
    const u16* __restrict__ wTl, const float* __restrict__ bias,
    float* __restrict__ out) {
  int wave = threadIdx.x >> 6, lane = threadIdx.x & 63;
  int row0 = blockIdx.x * 64 + wave * 16;
  int m = lane & 15, kq = lane >> 4;
  int rowA = row0 + m;
  if (rowA >= N_NODES) rowA = N_NODES - 1;
  const u16* hr = hcat + (size_t)rowA * HSTRIDE;

  v4f acc[3];
#pragma unroll
  for (int nf = 0; nf < 3; nf++) acc[nf] = (v4f){0.f, 0.f, 0.f, 0.f};

#pragma unroll 2
  for (int k0 = 0; k0 < HSTRIDE; k0 += 32) {
    int kk = k0 + kq * 8;
    v8s a = *(const v8s*)(hr + kk);
#pragma unroll
    for (int nf = 0; nf < 3; nf++) {
      int col = nf * 16 + m;
      v8s bh = *(const v8s*)(wTh + (size_t)col * HSTRIDE + kk);
      v8s bl = *(const v8s*)(wTl + (size_t)col * HSTRIDE + kk);
      acc[nf] = __builtin_amdgcn_mfma_f32_16x16x32_bf16(a, bh, acc[nf], 0, 0, 0);
      acc[nf] = __builtin_amdgcn_mfma_f32_16x16x32_bf16(a, bl, acc[nf], 0, 0, 0);
    }
  }

#pragma unroll
  for (int nf = 0; nf < 3; nf++) {
    int col = nf * 16 + m;
    if (col < OUT_DIM) {
      float bv = bias[col];
#pragma unroll
      for (int reg = 0; reg < 4; reg++) {
        int rowC = row0 + kq * 4 + reg;
        if (rowC < N_NODES)
          out[(size_t)rowC * OUT_DIM + col] = acc[nf][reg] + bv;
      }
    }
  }
}

// ---------------------------------------------------------------------------
extern "C" void kernel_launch(void* const* d_in, const int* in_sizes, int n_in,
                              void* d_out, int out_size, void* d_ws,
                              size_t ws_size, hipStream_t stream) {
  const float* x       = (const float*)d_in[0];
  const int*   src1    = (const int*)d_in[1];
  const int*   dst1    = (const int*)d_in[2];
  const float* w1      = (const float*)d_in[3];
  const int*   src2    = (const int*)d_in[4];
  const int*   dst2    = (const int*)d_in[5];
  const float* w2      = (const float*)d_in[6];
  const float* embed_w = (const float*)d_in[7];
  const float* embed_b = (const float*)d_in[8];
  const float* cls_w   = (const float*)d_in[9];
  const float* cls_b   = (const float*)d_in[10];
  int E1 = in_sizes[1];
  int E2 = in_sizes[4];

  float* ws = (float*)d_ws;
  size_t off = 0;
  u16* hcat = (u16*)(ws + off); off += (size_t)N_NODES * HSTRIDE / 2;
  int2* ew1 = (int2*)(ws + off); off += (size_t)2 * E1;
  int2* ew2 = (int2*)(ws + off); off += (size_t)2 * E2;
  int* ep1 = (int*)(ws + off); off += N_NODES;
  int* ep2 = (int*)(ws + off); off += N_NODES;
  int2* stg1 = (int2*)(ws + off); off += (size_t)2 * NBINS * CAP1;
  int2* stg2 = (int2*)(ws + off); off += (size_t)2 * NBINS * CAP2;
  int* binCursor = (int*)(ws + off); off += 2 * NBINS;
  int* binScan = (int*)(ws + off); off += 2 * NBINS;
  u16* weTh = (u16*)(ws + off); off += 16384;
  u16* weTl = (u16*)(ws + off); off += 16384;
  u16* wcTh = (u16*)(ws + off); off += 10752;
  u16* wcTl = (u16*)(ws + off); off += 10752;

  int c1 = (E1 + CHUNK - 1) / CHUNK;
  int c2 = (E2 + CHUNK - 1) / CHUNK;

  hipMemsetAsync(binCursor, 0, 2 * NBINS * sizeof(int), stream);
  prep_scatter<<<27 + c1 + c2, 256, 0, stream>>>(
      embed_w, weTh, weTl, cls_w, wcTh, wcTl,
      src1, dst1, w1, E1, c1, src2, dst2, w2, E2,
      binCursor, stg1, stg2);
  binscan<<<2, 512, 0, stream>>>(binCursor, binScan);
  embed_place<<<782 + 2 * NBINS, 256, 0, stream>>>(
      x, weTh, weTl, embed_b, hcat, binCursor, binScan,
      stg1, ew1, ep1, stg2, ew2, ep2);
  // k=1: cols 64:128 <- A1 @ hcat[:,0:64]; cols 128:192 <- A2 @ same
  gather2<8><<<3126, 256, 0, stream>>>(ep1, ew1, ep2, ew2, hcat,
                                       hcat + 64, hcat + 128, 1563);
  // k=2: cols 192:320 <- A1 @ hcat[:,64:192]; cols 320:448 <- A2 @ same
  gather2<16><<<6250, 256, 0, stream>>>(ep1, ew1, ep2, ew2, hcat + 64,
                                        hcat + 192, hcat + 320, 3125);
  final_mfma<<<782, 256, 0, stream>>>(hcat, wcTh, wcTl, cls_b, (float*)d_out);
}

// Round 13
// 260.700 us; speedup vs baseline: 1.0649x; 1.0102x over previous
//
#include <hip/hip_runtime.h>

#define N_NODES 50000
#define IN_DIM 512
#define HIDDEN 64
#define OUT_DIM 47
#define HSTRIDE 448  // hcat row stride (bf16): [h0(64) | hA(128) | hB(256)]

#define NBINS 391    // ceil(50000/128); bin = dst >> 7
#define CAP1 3072
#define CAP2 4096
#define CHUNK 4096

typedef unsigned short u16;
typedef short v8s __attribute__((ext_vector_type(8)));
typedef float v4f __attribute__((ext_vector_type(4)));

union F4 { float4 v; float f[4]; };
union U4 { uint4 v; unsigned u[4]; };

static __device__ __forceinline__ u16 f2bf(float f) {
  unsigned u = __float_as_uint(f);
  u += 0x7fffu + ((u >> 16) & 1u);
  return (u16)(u >> 16);
}
static __device__ __forceinline__ float bf2f(u16 h) {
  return __uint_as_float(((unsigned)h) << 16);
}

// ---------------------------------------------------------------------------
// conv_w: [0,16) embed_w -> wT hi/lo; [16,27) cls_w -> wT hi/lo. Tiny kernel.
// ---------------------------------------------------------------------------
__global__ __launch_bounds__(256) void conv_w(
    const float* __restrict__ embed_w, u16* __restrict__ weTh,
    u16* __restrict__ weTl, const float* __restrict__ cls_w,
    u16* __restrict__ wcTh, u16* __restrict__ wcTl) {
  int b = blockIdx.x;
  if (b < 16) {
    int tid = b * 256 + threadIdx.x;  // 64 cols * 64 kgroups
    int col = tid >> 6;
    int k8 = (tid & 63) * 8;
#pragma unroll
    for (int j = 0; j < 8; j++) {
      float v = embed_w[(size_t)(k8 + j) * HIDDEN + col];
      u16 h = f2bf(v);
      weTh[(size_t)col * IN_DIM + k8 + j] = h;
      weTl[(size_t)col * IN_DIM + k8 + j] = f2bf(v - bf2f(h));
    }
  } else {
    int tid = (b - 16) * 256 + threadIdx.x;  // 48 cols * 56 kgroups
    if (tid < 48 * 56) {
      int col = tid / 56;
      int k8 = (tid % 56) * 8;
#pragma unroll
      for (int j = 0; j < 8; j++) {
        float v = (col < OUT_DIM) ? cls_w[(size_t)(k8 + j) * OUT_DIM + col] : 0.f;
        u16 h = f2bf(v);
        wcTh[(size_t)col * HSTRIDE + k8 + j] = h;
        wcTl[(size_t)col * HSTRIDE + k8 + j] = f2bf(v - bf2f(h));
      }
    }
  }
}

// ---------------------------------------------------------------------------
// embed_bin (fused, independent halves): blocks [0,782) = embed MFMA ->
// hcat[:,0:64] bf16 (r10 inner loop); blocks [782,782+c1+c2) = binned edge
// scatter into staging (one global atomic per block,bin).
// embed A: fp32 x -> single bf16 convert; B hi/lo split (2 MFMA/nf).
// C/D: col=lane&15, row=(lane>>4)*4+reg  [m89-verified]
// ---------------------------------------------------------------------------
__global__ __launch_bounds__(256) void embed_bin(
    const float* __restrict__ x, const u16* __restrict__ wTh,
    const u16* __restrict__ wTl, const float* __restrict__ bias,
    u16* __restrict__ hcat,
    const int* __restrict__ src1, const int* __restrict__ dst1,
    const float* __restrict__ w1, int E1, int c1,
    const int* __restrict__ src2, const int* __restrict__ dst2,
    const float* __restrict__ w2, int E2,
    int* __restrict__ binCursor, int2* __restrict__ stg1,
    int2* __restrict__ stg2) {
  int b = blockIdx.x;
  if (b < 782) {
    int wave = threadIdx.x >> 6, lane = threadIdx.x & 63;
    int row0 = b * 64 + wave * 16;
    int m = lane & 15, kq = lane >> 4;
    int rowA = row0 + m;
    if (rowA >= N_NODES) rowA = N_NODES - 1;
    const float* xr = x + (size_t)rowA * IN_DIM;

    v4f acc[4];
#pragma unroll
    for (int nf = 0; nf < 4; nf++) acc[nf] = (v4f){0.f, 0.f, 0.f, 0.f};

#pragma unroll 4
    for (int k0 = 0; k0 < IN_DIM; k0 += 32) {
      int kk = k0 + kq * 8;
      F4 p, qv;
      p.v = *(const float4*)(xr + kk);
      qv.v = *(const float4*)(xr + kk + 4);
      v8s a;
#pragma unroll
      for (int j = 0; j < 4; j++) {
        a[j] = (short)f2bf(p.f[j]);
        a[4 + j] = (short)f2bf(qv.f[j]);
      }
#pragma unroll
      for (int nf = 0; nf < 4; nf++) {
        int col = nf * 16 + m;
        v8s bh = *(const v8s*)(wTh + (size_t)col * IN_DIM + kk);
        v8s bl = *(const v8s*)(wTl + (size_t)col * IN_DIM + kk);
        acc[nf] = __builtin_amdgcn_mfma_f32_16x16x32_bf16(a, bh, acc[nf], 0, 0, 0);
        acc[nf] = __builtin_amdgcn_mfma_f32_16x16x32_bf16(a, bl, acc[nf], 0, 0, 0);
      }
    }

#pragma unroll
    for (int nf = 0; nf < 4; nf++) {
      int col = nf * 16 + m;
      float bv = bias[col];
#pragma unroll
      for (int reg = 0; reg < 4; reg++) {
        int rowC = row0 + kq * 4 + reg;
        if (rowC < N_NODES) {
          float v = acc[nf][reg] + bv;
          hcat[(size_t)rowC * HSTRIDE + col] = f2bf(v > 0.f ? v : 0.f);
        }
      }
    }
    return;
  }

  int q = b - 782;
  const int *src, *dst;
  const float* w;
  int E, cap;
  int2* stg;
  int* bc;
  if (q < c1) {
    src = src1; dst = dst1; w = w1; E = E1; stg = stg1; bc = binCursor; cap = CAP1;
  } else {
    q -= c1;
    src = src2; dst = dst2; w = w2; E = E2; stg = stg2; bc = binCursor + NBINS; cap = CAP2;
  }
  int e0 = q * CHUNK;
  int n = E - e0;
  if (n > CHUNK) n = CHUNK;

  __shared__ int hist[NBINS], segrel[NBINS], cur[NBINS];
  for (int i = threadIdx.x; i < NBINS; i += 256) { hist[i] = 0; cur[i] = 0; }
  __syncthreads();
  for (int t = threadIdx.x; t < n; t += 256)
    atomicAdd(&hist[dst[e0 + t] >> 7], 1);
  __syncthreads();
  for (int i = threadIdx.x; i < NBINS; i += 256) {
    int h = hist[i];
    segrel[i] = h ? atomicAdd(&bc[i], h) : 0;
  }
  __syncthreads();
  for (int t = threadIdx.x; t < n; t += 256) {
    int d = dst[e0 + t];
    int bin = d >> 7;
    int rel = segrel[bin] + atomicAdd(&cur[bin], 1);
    if (rel < cap)
      stg[(size_t)bin * cap + rel] =
          make_int2(src[e0 + t] | ((d & 127) << 16), __float_as_int(w[e0 + t]));
  }
}

// ---------------------------------------------------------------------------
// binscan: exclusive scan of the NBINS bin counts per list (grid=2).
// ---------------------------------------------------------------------------
__global__ __launch_bounds__(512) void binscan(const int* __restrict__ cnt,
                                               int* __restrict__ scanout) {
  const int* in = cnt + blockIdx.x * NBINS;
  int* out = scanout + blockIdx.x * NBINS;
  int tid = threadIdx.x, lane = tid & 63, wid = tid >> 6;
  __shared__ int wsum[8];
  int v0 = (tid < NBINS) ? in[tid] : 0;
  int v = v0;
#pragma unroll
  for (int off = 1; off < 64; off <<= 1) {
    int t = __shfl_up(v, off, 64);
    if (lane >= off) v += t;
  }
  if (lane == 63) wsum[wid] = v;
  __syncthreads();
  if (tid < 8) {
    int s = wsum[tid], sc = s;
#pragma unroll
    for (int off = 1; off < 8; off <<= 1) {
      int t = __shfl_up(sc, off, 8);
      if (tid >= off) sc += t;
    }
    wsum[tid] = sc - s;
  }
  __syncthreads();
  if (tid < NBINS) out[tid] = v - v0 + wsum[wid];
}

// ---------------------------------------------------------------------------
// place (standalone): one block per (list,bin) — per-bin CSR placement.
// Writes ep (inclusive end-ptr) + ew (sorted edges).
// ---------------------------------------------------------------------------
__global__ __launch_bounds__(256) void place(
    const int* __restrict__ binCursor, const int* __restrict__ binScan,
    const int2* __restrict__ stg1, int2* __restrict__ ew1,
    int* __restrict__ ep1, const int2* __restrict__ stg2,
    int2* __restrict__ ew2, int* __restrict__ ep2) {
  int pb = blockIdx.x;
  int lb = pb < NBINS ? pb : pb - NBINS;
  const int2* stg;
  int2* ew;
  int* ep;
  int cap;
  if (pb < NBINS) { stg = stg1; ew = ew1; ep = ep1; cap = CAP1; }
  else            { stg = stg2; ew = ew2; ep = ep2; cap = CAP2; }
  int cnt = binCursor[pb];
  if (cnt > cap) cnt = cap;
  int base = binScan[pb];
  const int2* seg = stg + (size_t)lb * cap;
  int node0 = lb << 7;
  int nnodes = N_NODES - node0;
  if (nnodes > 128) nnodes = 128;

  __shared__ int ncnt[128], noff[128], ncur[128];
  __shared__ int t0;
  if (threadIdx.x < 128) { ncnt[threadIdx.x] = 0; ncur[threadIdx.x] = 0; }
  __syncthreads();
  for (int t = threadIdx.x; t < cnt; t += 256)
    atomicAdd(&ncnt[(seg[t].x >> 16) & 127], 1);
  __syncthreads();
  int v0 = 0, v = 0;
  if (threadIdx.x < 128) {
    v0 = ncnt[threadIdx.x];
    v = v0;
    int lane = threadIdx.x & 63;
#pragma unroll
    for (int off = 1; off < 64; off <<= 1) {
      int t = __shfl_up(v, off, 64);
      if (lane >= off) v += t;
    }
    if (threadIdx.x == 63) t0 = v;
  }
  __syncthreads();
  if (threadIdx.x < 128) {
    int excl = v - v0 + (threadIdx.x >= 64 ? t0 : 0);
    noff[threadIdx.x] = excl;
    if (threadIdx.x < nnodes) ep[node0 + threadIdx.x] = base + excl + v0;
  }
  __syncthreads();
  for (int t = threadIdx.x; t < cnt; t += 256) {
    int2 pk = seg[t];
    int nl = (pk.x >> 16) & 127;
    int pos = base + noff[nl] + atomicAdd(&ncur[nl], 1);
    ew[pos] = make_int2(pk.x & 0xFFFF, pk.y);
  }
}

// ---------------------------------------------------------------------------
// gather2 (fused pair): blocks [0,half) = list1 -> out1, rest = list2 -> out2.
// NT threads/node, each 8 bf16 cols (16B load/edge). fp32 acc, ReLU, bf16 out.
// ---------------------------------------------------------------------------
__device__ __forceinline__ void bf8_fma(const U4& r, float wt, float* a) {
#pragma unroll
  for (int i = 0; i < 4; i++) {
    a[2 * i]     += wt * __uint_as_float(r.u[i] << 16);
    a[2 * i + 1] += wt * __uint_as_float(r.u[i] & 0xffff0000u);
  }
}

template <int NT>
__global__ __launch_bounds__(256) void gather2(
    const int* __restrict__ ep1, const int2* __restrict__ ew1,
    const int* __restrict__ ep2, const int2* __restrict__ ew2,
    const u16* __restrict__ hin, u16* __restrict__ out1,
    u16* __restrict__ out2, int half_blocks) {
  int b = blockIdx.x;
  const int* ep;
  const int2* ew;
  u16* out;
  if (b < half_blocks) { ep = ep1; ew = ew1; out = out1; }
  else { b -= half_blocks; ep = ep2; ew = ew2; out = out2; }

  int tid = b * 256 + threadIdx.x;
  int node = tid / NT;
  if (node >= N_NODES) return;
  int col0 = (tid % NT) * 8;
  int s = node ? ep[node - 1] : 0;
  int e = ep[node];

  float a0[8], a1[8];
#pragma unroll
  for (int i = 0; i < 8; i++) { a0[i] = 0.f; a1[i] = 0.f; }

  int j = s;
  for (; j + 4 <= e; j += 4) {
    int2 p0 = ew[j], p1 = ew[j + 1], p2 = ew[j + 2], p3 = ew[j + 3];
    U4 r0, r1, r2, r3;
    r0.v = *(const uint4*)(hin + (size_t)p0.x * HSTRIDE + col0);
    r1.v = *(const uint4*)(hin + (size_t)p1.x * HSTRIDE + col0);
    r2.v = *(const uint4*)(hin + (size_t)p2.x * HSTRIDE + col0);
    r3.v = *(const uint4*)(hin + (size_t)p3.x * HSTRIDE + col0);
    bf8_fma(r0, __int_as_float(p0.y), a0);
    bf8_fma(r1, __int_as_float(p1.y), a1);
    bf8_fma(r2, __int_as_float(p2.y), a0);
    bf8_fma(r3, __int_as_float(p3.y), a1);
  }
  for (; j < e; j++) {
    int2 p = ew[j];
    U4 r;
    r.v = *(const uint4*)(hin + (size_t)p.x * HSTRIDE + col0);
    bf8_fma(r, __int_as_float(p.y), a0);
  }

  U4 o;
#pragma unroll
  for (int i = 0; i < 4; i++) {
    float lo = a0[2 * i] + a1[2 * i];
    float hi = a0[2 * i + 1] + a1[2 * i + 1];
    lo = lo > 0.f ? lo : 0.f;
    hi = hi > 0.f ? hi : 0.f;
    o.u[i] = ((unsigned)f2bf(hi) << 16) | (unsigned)f2bf(lo);
  }
  *(uint4*)(out + (size_t)node * HSTRIDE + col0) = o.v;
}

// ---------------------------------------------------------------------------
// final: out = hcat(bf16) @ cls_w + b. A direct bf16, B split hi/lo (2 MFMA).
// ---------------------------------------------------------------------------
__global__ __launch_bounds__(256) void final_mfma(
    const u16* __restrict__ hcat, const u16* __restrict__ wTh,
    const u16* __restrict__ wTl, const float* __restrict__ bias,
    float* __restrict__ out) {
  int wave = threadIdx.x >> 6, lane = threadIdx.x & 63;
  int row0 = blockIdx.x * 64 + wave * 16;
  int m = lane & 15, kq = lane >> 4;
  int rowA = row0 + m;
  if (rowA >= N_NODES) rowA = N_NODES - 1;
  const u16* hr = hcat + (size_t)rowA * HSTRIDE;

  v4f acc[3];
#pragma unroll
  for (int nf = 0; nf < 3; nf++) acc[nf] = (v4f){0.f, 0.f, 0.f, 0.f};

#pragma unroll 2
  for (int k0 = 0; k0 < HSTRIDE; k0 += 32) {
    int kk = k0 + kq * 8;
    v8s a = *(const v8s*)(hr + kk);
#pragma unroll
    for (int nf = 0; nf < 3; nf++) {
      int col = nf * 16 + m;
      v8s bh = *(const v8s*)(wTh + (size_t)col * HSTRIDE + kk);
      v8s bl = *(const v8s*)(wTl + (size_t)col * HSTRIDE + kk);
      acc[nf] = __builtin_amdgcn_mfma_f32_16x16x32_bf16(a, bh, acc[nf], 0, 0, 0);
      acc[nf] = __builtin_amdgcn_mfma_f32_16x16x32_bf16(a, bl, acc[nf], 0, 0, 0);
    }
  }

#pragma unroll
  for (int nf = 0; nf < 3; nf++) {
    int col = nf * 16 + m;
    if (col < OUT_DIM) {
      float bv = bias[col];
#pragma unroll
      for (int reg = 0; reg < 4; reg++) {
        int rowC = row0 + kq * 4 + reg;
        if (rowC < N_NODES)
          out[(size_t)rowC * OUT_DIM + col] = acc[nf][reg] + bv;
      }
    }
  }
}

// ---------------------------------------------------------------------------
extern "C" void kernel_launch(void* const* d_in, const int* in_sizes, int n_in,
                              void* d_out, int out_size, void* d_ws,
                              size_t ws_size, hipStream_t stream) {
  const float* x       = (const float*)d_in[0];
  const int*   src1    = (const int*)d_in[1];
  const int*   dst1    = (const int*)d_in[2];
  const float* w1      = (const float*)d_in[3];
  const int*   src2    = (const int*)d_in[4];
  const int*   dst2    = (const int*)d_in[5];
  const float* w2      = (const float*)d_in[6];
  const float* embed_w = (const float*)d_in[7];
  const float* embed_b = (const float*)d_in[8];
  const float* cls_w   = (const float*)d_in[9];
  const float* cls_b   = (const float*)d_in[10];
  int E1 = in_sizes[1];
  int E2 = in_sizes[4];

  float* ws = (float*)d_ws;
  size_t off = 0;
  u16* hcat = (u16*)(ws + off); off += (size_t)N_NODES * HSTRIDE / 2;
  int2* ew1 = (int2*)(ws + off); off += (size_t)2 * E1;
  int2* ew2 = (int2*)(ws + off); off += (size_t)2 * E2;
  int* ep1 = (int*)(ws + off); off += N_NODES;
  int* ep2 = (int*)(ws + off); off += N_NODES;
  int2* stg1 = (int2*)(ws + off); off += (size_t)2 * NBINS * CAP1;
  int2* stg2 = (int2*)(ws + off); off += (size_t)2 * NBINS * CAP2;
  int* binCursor = (int*)(ws + off); off += 2 * NBINS;
  int* binScan = (int*)(ws + off); off += 2 * NBINS;
  u16* weTh = (u16*)(ws + off); off += 16384;
  u16* weTl = (u16*)(ws + off); off += 16384;
  u16* wcTh = (u16*)(ws + off); off += 10752;
  u16* wcTl = (u16*)(ws + off); off += 10752;

  int c1 = (E1 + CHUNK - 1) / CHUNK;
  int c2 = (E2 + CHUNK - 1) / CHUNK;

  hipMemsetAsync(binCursor, 0, 2 * NBINS * sizeof(int), stream);
  conv_w<<<27, 256, 0, stream>>>(embed_w, weTh, weTl, cls_w, wcTh, wcTl);
  embed_bin<<<782 + c1 + c2, 256, 0, stream>>>(
      x, weTh, weTl, embed_b, hcat,
      src1, dst1, w1, E1, c1, src2, dst2, w2, E2,
      binCursor, stg1, stg2);
  binscan<<<2, 512, 0, stream>>>(binCursor, binScan);
  place<<<2 * NBINS, 256, 0, stream>>>(binCursor, binScan,
                                       stg1, ew1, ep1, stg2, ew2, ep2);
  // k=1: cols 64:128 <- A1 @ hcat[:,0:64]; cols 128:192 <- A2 @ same
  gather2<8><<<3126, 256, 0, stream>>>(ep1, ew1, ep2, ew2, hcat,
                                       hcat + 64, hcat + 128, 1563);
  // k=2: cols 192:320 <- A1 @ hcat[:,64:192]; cols 320:448 <- A2 @ same
  gather2<16><<<6250, 256, 0, stream>>>(ep1, ew1, ep2, ew2, hcat + 64,
                                        hcat + 192, hcat + 320, 3125);
  final_mfma<<<782, 256, 0, stream>>>(hcat, wcTh, wcTl, cls_b, (float*)d_out);
}

// Round 14
// 253.408 us; speedup vs baseline: 1.0955x; 1.0288x over previous
//
#include <hip/hip_runtime.h>

#define N_NODES 50000
#define IN_DIM 512
#define HIDDEN 64
#define OUT_DIM 47
#define HSTRIDE 448  // hcat row stride (bf16): [h0(64) | hA(128) | hB(256)]

#define NBINS 391    // ceil(50000/128); bin = dst >> 7
#define CAP1 3072
#define CAP2 4096
#define CHUNK 4096

typedef unsigned short u16;
typedef short v8s __attribute__((ext_vector_type(8)));
typedef float v4f __attribute__((ext_vector_type(4)));

union F4 { float4 v; float f[4]; };
union U4 { uint4 v; unsigned u[4]; };

static __device__ __forceinline__ u16 f2bf(float f) {
  unsigned u = __float_as_uint(f);
  u += 0x7fffu + ((u >> 16) & 1u);
  return (u16)(u >> 16);
}
static __device__ __forceinline__ float bf2f(u16 h) {
  return __uint_as_float(((unsigned)h) << 16);
}

// async 16B global -> LDS (CK-style addrspace casts; size must be literal 16)
static __device__ __forceinline__ void load_lds16(const float* g, void* l) {
  __builtin_amdgcn_global_load_lds(
      reinterpret_cast<const __attribute__((address_space(1))) unsigned int*>(
          reinterpret_cast<uintptr_t>(g)),
      reinterpret_cast<__attribute__((address_space(3))) unsigned int*>(
          reinterpret_cast<uintptr_t>(l)),
      16, 0, 0);
}

// ---------------------------------------------------------------------------
// conv_w: [0,16) embed_w -> wT hi/lo; [16,27) cls_w -> wT hi/lo. Tiny kernel.
// ---------------------------------------------------------------------------
__global__ __launch_bounds__(256) void conv_w(
    const float* __restrict__ embed_w, u16* __restrict__ weTh,
    u16* __restrict__ weTl, const float* __restrict__ cls_w,
    u16* __restrict__ wcTh, u16* __restrict__ wcTl) {
  int b = blockIdx.x;
  if (b < 16) {
    int tid = b * 256 + threadIdx.x;  // 64 cols * 64 kgroups
    int col = tid >> 6;
    int k8 = (tid & 63) * 8;
#pragma unroll
    for (int j = 0; j < 8; j++) {
      float v = embed_w[(size_t)(k8 + j) * HIDDEN + col];
      u16 h = f2bf(v);
      weTh[(size_t)col * IN_DIM + k8 + j] = h;
      weTl[(size_t)col * IN_DIM + k8 + j] = f2bf(v - bf2f(h));
    }
  } else {
    int tid = (b - 16) * 256 + threadIdx.x;  // 48 cols * 56 kgroups
    if (tid < 48 * 56) {
      int col = tid / 56;
      int k8 = (tid % 56) * 8;
#pragma unroll
      for (int j = 0; j < 8; j++) {
        float v = (col < OUT_DIM) ? cls_w[(size_t)(k8 + j) * OUT_DIM + col] : 0.f;
        u16 h = f2bf(v);
        wcTh[(size_t)col * HSTRIDE + k8 + j] = h;
        wcTl[(size_t)col * HSTRIDE + k8 + j] = f2bf(v - bf2f(h));
      }
    }
  }
}

// ---------------------------------------------------------------------------
// embed_bin (fused): blocks [0,782) = embed MFMA with double-buffered
// global_load_lds x staging -> hcat[:,0:64] bf16; blocks [782,..) = binned
// edge scatter into staging (unchanged r13).
//
// LDS tile: [64 rows][32 k] fp32 = 8 KB, XOR-swizzled: chunk c (16B) of row r
// stored at slot c^(r&7). global_load_lds writes linearly (base+lane*16), so
// the SOURCE address is inverse-swizzled per lane (m201/m104 rule).
// A-frag read: lane(m,kq) reads slots (2kq)^(r&7), ^1 -> 2-way conflict (free).
// C/D: col=lane&15, row=(lane>>4)*4+reg  [m89-verified]
// ---------------------------------------------------------------------------
__global__ __launch_bounds__(256) void embed_bin(
    const float* __restrict__ x, const u16* __restrict__ wTh,
    const u16* __restrict__ wTl, const float* __restrict__ bias,
    u16* __restrict__ hcat,
    const int* __restrict__ src1, const int* __restrict__ dst1,
    const float* __restrict__ w1, int E1, int c1,
    const int* __restrict__ src2, const int* __restrict__ dst2,
    const float* __restrict__ w2, int E2,
    int* __restrict__ binCursor, int2* __restrict__ stg1,
    int2* __restrict__ stg2) {
  __shared__ float4 xtile4[1024];  // 2 x 8 KB double buffer
  __shared__ int hist[NBINS], segrel[NBINS], cur[NBINS];
  int b = blockIdx.x;
  if (b < 782) {
    float* xtile = (float*)xtile4;
    int wave = threadIdx.x >> 6, lane = threadIdx.x & 63;
    int row0 = b * 64;
    int m = lane & 15, kq = lane >> 4;

    // staging lane geometry (fixed per thread)
    int seg0 = wave * 2;                 // two 1KB segments per wave
    int sr0 = seg0 * 8 + (lane >> 3);    // LDS row for instr 0
    int sr1 = sr0 + 8;                   // LDS row for instr 1
    int sc0 = (lane & 7) ^ (sr0 & 7);    // inverse-swizzled source chunk
    int sc1 = (lane & 7) ^ (sr1 & 7);
    int gr0 = row0 + sr0; if (gr0 >= N_NODES) gr0 = N_NODES - 1;
    int gr1 = row0 + sr1; if (gr1 >= N_NODES) gr1 = N_NODES - 1;
    const float* g0 = x + (size_t)gr0 * IN_DIM + sc0 * 4;
    const float* g1 = x + (size_t)gr1 * IN_DIM + sc1 * 4;

    v4f acc[4];
#pragma unroll
    for (int nf = 0; nf < 4; nf++) acc[nf] = (v4f){0.f, 0.f, 0.f, 0.f};

    int r = wave * 16 + m;
    int slotA = (2 * kq) ^ (r & 7);
    int slotB = slotA ^ 1;
    const float* rbase0 = (const float*)xtile + r * 32;
    const float* rbase1 = rbase0 + 2048;  // second buffer (8KB/4)

    // prologue: stage tile 0 into buf 0
    load_lds16(g0, (char*)xtile + seg0 * 1024 + (lane & 7) * 0 + 0 + (size_t)0 +
                       (sr0 - seg0 * 8) * 0);  // placeholder no-op math removed below
    // (real calls below — keep addressing simple)
    __syncthreads();  // dummy sync replaced: real prologue follows

    // NOTE: restart clean prologue (the above call staged chunk for instr0
    // at buf0 base of this wave's segment; issue instr1 too)
    load_lds16(g1, (char*)xtile + (seg0 + 1) * 1024);
    __syncthreads();

#pragma unroll 2
    for (int t = 0; t < 16; t++) {
      if (t < 15) {
        int k0n = (t + 1) * 32;
        int bufn = (t + 1) & 1;
        load_lds16(g0 + k0n, (char*)xtile + bufn * 8192 + seg0 * 1024);
        load_lds16(g1 + k0n, (char*)xtile + bufn * 8192 + (seg0 + 1) * 1024);
      }
      const float* rb = (t & 1) ? rbase1 : rbase0;
      F4 p, q;
      p.v = *(const float4*)(rb + slotA * 4);
      q.v = *(const float4*)(rb + slotB * 4);
      v8s a;
#pragma unroll
      for (int j = 0; j < 4; j++) {
        a[j] = (short)f2bf(p.f[j]);
        a[4 + j] = (short)f2bf(q.f[j]);
      }
      int kk = t * 32 + kq * 8;
#pragma unroll
      for (int nf = 0; nf < 4; nf++) {
        int col = nf * 16 + m;
        v8s bh = *(const v8s*)(wTh + (size_t)col * IN_DIM + kk);
        v8s bl = *(const v8s*)(wTl + (size_t)col * IN_DIM + kk);
        acc[nf] = __builtin_amdgcn_mfma_f32_16x16x32_bf16(a, bh, acc[nf], 0, 0, 0);
        acc[nf] = __builtin_amdgcn_mfma_f32_16x16x32_bf16(a, bl, acc[nf], 0, 0, 0);
      }
      __syncthreads();
    }

#pragma unroll
    for (int nf = 0; nf < 4; nf++) {
      int col = nf * 16 + m;
      float bv = bias[col];
#pragma unroll
      for (int reg = 0; reg < 4; reg++) {
        int rowC = row0 + wave * 16 + kq * 4 + reg;
        if (rowC < N_NODES) {
          float v = acc[nf][reg] + bv;
          hcat[(size_t)rowC * HSTRIDE + col] = f2bf(v > 0.f ? v : 0.f);
        }
      }
    }
    return;
  }

  int q = b - 782;
  const int *src, *dst;
  const float* w;
  int E, cap;
  int2* stg;
  int* bc;
  if (q < c1) {
    src = src1; dst = dst1; w = w1; E = E1; stg = stg1; bc = binCursor; cap = CAP1;
  } else {
    q -= c1;
    src = src2; dst = dst2; w = w2; E = E2; stg = stg2; bc = binCursor + NBINS; cap = CAP2;
  }
  int e0 = q * CHUNK;
  int n = E - e0;
  if (n > CHUNK) n = CHUNK;

  for (int i = threadIdx.x; i < NBINS; i += 256) { hist[i] = 0; cur[i] = 0; }
  __syncthreads();
  for (int t = threadIdx.x; t < n; t += 256)
    atomicAdd(&hist[dst[e0 + t] >> 7], 1);
  __syncthreads();
  for (int i = threadIdx.x; i < NBINS; i += 256) {
    int h = hist[i];
    segrel[i] = h ? atomicAdd(&bc[i], h) : 0;
  }
  __syncthreads();
  for (int t = threadIdx.x; t < n; t += 256) {
    int d = dst[e0 + t];
    int bin = d >> 7;
    int rel = segrel[bin] + atomicAdd(&cur[bin], 1);
    if (rel < cap)
      stg[(size_t)bin * cap + rel] =
          make_int2(src[e0 + t] | ((d & 127) << 16), __float_as_int(w[e0 + t]));
  }
}

// ---------------------------------------------------------------------------
// binscan: exclusive scan of the NBINS bin counts per list (grid=2).
// ---------------------------------------------------------------------------
__global__ __launch_bounds__(512) void binscan(const int* __restrict__ cnt,
                                               int* __restrict__ scanout) {
  const int* in = cnt + blockIdx.x * NBINS;
  int* out = scanout + blockIdx.x * NBINS;
  int tid = threadIdx.x, lane = tid & 63, wid = tid >> 6;
  __shared__ int wsum[8];
  int v0 = (tid < NBINS) ? in[tid] : 0;
  int v = v0;
#pragma unroll
  for (int off = 1; off < 64; off <<= 1) {
    int t = __shfl_up(v, off, 64);
    if (lane >= off) v += t;
  }
  if (lane == 63) wsum[wid] = v;
  __syncthreads();
  if (tid < 8) {
    int s = wsum[tid], sc = s;
#pragma unroll
    for (int off = 1; off < 8; off <<= 1) {
      int t = __shfl_up(sc, off, 8);
      if (tid >= off) sc += t;
    }
    wsum[tid] = sc - s;
  }
  __syncthreads();
  if (tid < NBINS) out[tid] = v - v0 + wsum[wid];
}

// ---------------------------------------------------------------------------
// place (standalone): one block per (list,bin) — per-bin CSR placement.
// ---------------------------------------------------------------------------
__global__ __launch_bounds__(256) void place(
    const int* __restrict__ binCursor, const int* __restrict__ binScan,
    const int2* __restrict__ stg1, int2* __restrict__ ew1,
    int* __restrict__ ep1, const int2* __restrict__ stg2,
    int2* __restrict__ ew2, int* __restrict__ ep2) {
  int pb = blockIdx.x;
  int lb = pb < NBINS ? pb : pb - NBINS;
  const int2* stg;
  int2* ew;
  int* ep;
  int cap;
  if (pb < NBINS) { stg = stg1; ew = ew1; ep = ep1; cap = CAP1; }
  else            { stg = stg2; ew = ew2; ep = ep2; cap = CAP2; }
  int cnt = binCursor[pb];
  if (cnt > cap) cnt = cap;
  int base = binScan[pb];
  const int2* seg = stg + (size_t)lb * cap;
  int node0 = lb << 7;
  int nnodes = N_NODES - node0;
  if (nnodes > 128) nnodes = 128;

  __shared__ int ncnt[128], noff[128], ncur[128];
  __shared__ int t0;
  if (threadIdx.x < 128) { ncnt[threadIdx.x] = 0; ncur[threadIdx.x] = 0; }
  __syncthreads();
  for (int t = threadIdx.x; t < cnt; t += 256)
    atomicAdd(&ncnt[(seg[t].x >> 16) & 127], 1);
  __syncthreads();
  int v0 = 0, v = 0;
  if (threadIdx.x < 128) {
    v0 = ncnt[threadIdx.x];
    v = v0;
    int lane = threadIdx.x & 63;
#pragma unroll
    for (int off = 1; off < 64; off <<= 1) {
      int t = __shfl_up(v, off, 64);
      if (lane >= off) v += t;
    }
    if (threadIdx.x == 63) t0 = v;
  }
  __syncthreads();
  if (threadIdx.x < 128) {
    int excl = v - v0 + (threadIdx.x >= 64 ? t0 : 0);
    noff[threadIdx.x] = excl;
    if (threadIdx.x < nnodes) ep[node0 + threadIdx.x] = base + excl + v0;
  }
  __syncthreads();
  for (int t = threadIdx.x; t < cnt; t += 256) {
    int2 pk = seg[t];
    int nl = (pk.x >> 16) & 127;
    int pos = base + noff[nl] + atomicAdd(&ncur[nl], 1);
    ew[pos] = make_int2(pk.x & 0xFFFF, pk.y);
  }
}

// ---------------------------------------------------------------------------
// gather2 (fused pair): blocks [0,half) = list1 -> out1, rest = list2 -> out2.
// ---------------------------------------------------------------------------
__device__ __forceinline__ void bf8_fma(const U4& r, float wt, float* a) {
#pragma unroll
  for (int i = 0; i < 4; i++) {
    a[2 * i]     += wt * __uint_as_float(r.u[i] << 16);
    a[2 * i + 1] += wt * __uint_as_float(r.u[i] & 0xffff0000u);
  }
}

template <int NT>
__global__ __launch_bounds__(256) void gather2(
    const int* __restrict__ ep1, const int2* __restrict__ ew1,
    const int* __restrict__ ep2, const int2* __restrict__ ew2,
    const u16* __restrict__ hin, u16* __restrict__ out1,
    u16* __restrict__ out2, int half_blocks) {
  int b = blockIdx.x;
  const int* ep;
  const int2* ew;
  u16* out;
  if (b < half_blocks) { ep = ep1; ew = ew1; out = out1; }
  else { b -= half_blocks; ep = ep2; ew = ew2; out = out2; }

  int tid = b * 256 + threadIdx.x;
  int node = tid / NT;
  if (node >= N_NODES) return;
  int col0 = (tid % NT) * 8;
  int s = node ? ep[node - 1] : 0;
  int e = ep[node];

  float a0[8], a1[8];
#pragma unroll
  for (int i = 0; i < 8; i++) { a0[i] = 0.f; a1[i] = 0.f; }

  int j = s;
  for (; j + 4 <= e; j += 4) {
    int2 p0 = ew[j], p1 = ew[j + 1], p2 = ew[j + 2], p3 = ew[j + 3];
    U4 r0, r1, r2, r3;
    r0.v = *(const uint4*)(hin + (size_t)p0.x * HSTRIDE + col0);
    r1.v = *(const uint4*)(hin + (size_t)p1.x * HSTRIDE + col0);
    r2.v = *(const uint4*)(hin + (size_t)p2.x * HSTRIDE + col0);
    r3.v = *(const uint4*)(hin + (size_t)p3.x * HSTRIDE + col0);
    bf8_fma(r0, __int_as_float(p0.y), a0);
    bf8_fma(r1, __int_as_float(p1.y), a1);
    bf8_fma(r2, __int_as_float(p2.y), a0);
    bf8_fma(r3, __int_as_float(p3.y), a1);
  }
  for (; j < e; j++) {
    int2 p = ew[j];
    U4 r;
    r.v = *(const uint4*)(hin + (size_t)p.x * HSTRIDE + col0);
    bf8_fma(r, __int_as_float(p.y), a0);
  }

  U4 o;
#pragma unroll
  for (int i = 0; i < 4; i++) {
    float lo = a0[2 * i] + a1[2 * i];
    float hi = a0[2 * i + 1] + a1[2 * i + 1];
    lo = lo > 0.f ? lo : 0.f;
    hi = hi > 0.f ? hi : 0.f;
    o.u[i] = ((unsigned)f2bf(hi) << 16) | (unsigned)f2bf(lo);
  }
  *(uint4*)(out + (size_t)node * HSTRIDE + col0) = o.v;
}

// ---------------------------------------------------------------------------
// final: out = hcat(bf16) @ cls_w + b. A direct bf16, B split hi/lo (2 MFMA).
// ---------------------------------------------------------------------------
__global__ __launch_bounds__(256) void final_mfma(
    const u16* __restrict__ hcat, const u16* __restrict__ wTh,
    const u16* __restrict__ wTl, const float* __restrict__ bias,
    float* __restrict__ out) {
  int wave = threadIdx.x >> 6, lane = threadIdx.x & 63;
  int row0 = blockIdx.x * 64 + wave * 16;
  int m = lane & 15, kq = lane >> 4;
  int rowA = row0 + m;
  if (rowA >= N_NODES) rowA = N_NODES - 1;
  const u16* hr = hcat + (size_t)rowA * HSTRIDE;

  v4f acc[3];
#pragma unroll
  for (int nf = 0; nf < 3; nf++) acc[nf] = (v4f){0.f, 0.f, 0.f, 0.f};

#pragma unroll 2
  for (int k0 = 0; k0 < HSTRIDE; k0 += 32) {
    int kk = k0 + kq * 8;
    v8s a = *(const v8s*)(hr + kk);
#pragma unroll
    for (int nf = 0; nf < 3; nf++) {
      int col = nf * 16 + m;
      v8s bh = *(const v8s*)(wTh + (size_t)col * HSTRIDE + kk);
      v8s bl = *(const v8s*)(wTl + (size_t)col * HSTRIDE + kk);
      acc[nf] = __builtin_amdgcn_mfma_f32_16x16x32_bf16(a, bh, acc[nf], 0, 0, 0);
      acc[nf] = __builtin_amdgcn_mfma_f32_16x16x32_bf16(a, bl, acc[nf], 0, 0, 0);
    }
  }

#pragma unroll
  for (int nf = 0; nf < 3; nf++) {
    int col = nf * 16 + m;
    if (col < OUT_DIM) {
      float bv = bias[col];
#pragma unroll
      for (int reg = 0; reg < 4; reg++) {
        int rowC = row0 + kq * 4 + reg;
        if (rowC < N_NODES)
          out[(size_t)rowC * OUT_DIM + col] = acc[nf][reg] + bv;
      }
    }
  }
}

// ---------------------------------------------------------------------------
extern "C" void kernel_launch(void* const* d_in, const int* in_sizes, int n_in,
                              void* d_out, int out_size, void* d_ws,
                              size_t ws_size, hipStream_t stream) {
  const float* x       = (const float*)d_in[0];
  const int*   src1    = (const int*)d_in[1];
  const int*   dst1    = (const int*)d_in[2];
  const float* w1      = (const float*)d_in[3];
  const int*   src2    = (const int*)d_in[4];
  const int*   dst2    = (const int*)d_in[5];
  const float* w2      = (const float*)d_in[6];
  const float* embed_w = (const float*)d_in[7];
  const float* embed_b = (const float*)d_in[8];
  const float* cls_w   = (const float*)d_in[9];
  const float* cls_b   = (const float*)d_in[10];
  int E1 = in_sizes[1];
  int E2 = in_sizes[4];

  float* ws = (float*)d_ws;
  size_t off = 0;
  u16* hcat = (u16*)(ws + off); off += (size_t)N_NODES * HSTRIDE / 2;
  int2* ew1 = (int2*)(ws + off); off += (size_t)2 * E1;
  int2* ew2 = (int2*)(ws + off); off += (size_t)2 * E2;
  int* ep1 = (int*)(ws + off); off += N_NODES;
  int* ep2 = (int*)(ws + off); off += N_NODES;
  int2* stg1 = (int2*)(ws + off); off += (size_t)2 * NBINS * CAP1;
  int2* stg2 = (int2*)(ws + off); off += (size_t)2 * NBINS * CAP2;
  int* binCursor = (int*)(ws + off); off += 2 * NBINS;
  int* binScan = (int*)(ws + off); off += 2 * NBINS;
  u16* weTh = (u16*)(ws + off); off += 16384;
  u16* weTl = (u16*)(ws + off); off += 16384;
  u16* wcTh = (u16*)(ws + off); off += 10752;
  u16* wcTl = (u16*)(ws + off); off += 10752;

  int c1 = (E1 + CHUNK - 1) / CHUNK;
  int c2 = (E2 + CHUNK - 1) / CHUNK;

  hipMemsetAsync(binCursor, 0, 2 * NBINS * sizeof(int), stream);
  conv_w<<<27, 256, 0, stream>>>(embed_w, weTh, weTl, cls_w, wcTh, wcTl);
  embed_bin<<<782 + c1 + c2, 256, 0, stream>>>(
      x, weTh, weTl, embed_b, hcat,
      src1, dst1, w1, E1, c1, src2, dst2, w2, E2,
      binCursor, stg1, stg2);
  binscan<<<2, 512, 0, stream>>>(binCursor, binScan);
  place<<<2 * NBINS, 256, 0, stream>>>(binCursor, binScan,
                                       stg1, ew1, ep1, stg2, ew2, ep2);
  // k=1: cols 64:128 <- A1 @ hcat[:,0:64]; cols 128:192 <- A2 @ same
  gather2<8><<<3126, 256, 0, stream>>>(ep1, ew1, ep2, ew2, hcat,
                                       hcat + 64, hcat + 128, 1563);
  // k=2: cols 192:320 <- A1 @ hcat[:,64:192]; cols 320:448 <- A2 @ same
  gather2<16><<<6250, 256, 0, stream>>>(ep1, ew1, ep2, ew2, hcat + 64,
                                        hcat + 192, hcat + 320, 3125);
  final_mfma<<<782, 256, 0, stream>>>(hcat, wcTh, wcTl, cls_b, (float*)d_out);
}